// Round 4
// baseline (80.727 us; speedup 1.0000x reference)
//
#include <hip/hip_runtime.h>
#include <hip/hip_bf16.h>
#include <cstdint>

// DLM breadth-2 forward. B=16, n=128, C=64.
// out = [out0 (16*64) | out1 (16*128*64) | out2 (16*128*128*64)], fp32.
//
// out2[b,i,j,c] = sigmoid( PA[b,i,c] + PB[b,j,c]
//                          + x2[b,i,j,:]·W2[64:128,c] + x2[b,j,i,:]·W2[192:256,c] )
// with PA = x1·W2[0:64] + b2, PB = x1·W2[128:192]  (precomputed).
//
// k_pair: symmetric supertile blocks. Supertile (b, gI, gJ) (16-row groups,
// gI<=gJ) computes out2[b,I,J,:] and out2[b,J,I,:], reading x2[b,I,J] and
// x2[b,J,I] exactly once each (contiguous 4KB chunks on one role, L2-hot on
// the transposed role). W is the MFMA A-operand, x2 the B-operand -> B-frags
// load straight from global memory: ZERO LDS, zero barriers.
// out1 exclude-self max/min partials computed from the fp32 slab1 loads,
// reduced cross-lane, spilled to ws; tail kernel combines 8 group-partials.

#define NDIM 128
#define CDIM 64

typedef float f32x4 __attribute__((ext_vector_type(4)));
typedef short s16x8 __attribute__((ext_vector_type(8)));

__device__ __forceinline__ unsigned short f2bf(float f) {
    union { float f; unsigned int u; } v; v.f = f;
    unsigned int u = v.u;
    return (unsigned short)((u + 0x7FFFu + ((u >> 16) & 1u)) >> 16);  // RNE
}
__device__ __forceinline__ float sigmoidf_(float x) {
    return 1.0f / (1.0f + __expf(-x));
}
__device__ __forceinline__ s16x8 pack_bf(f32x4 a, f32x4 b) {
    s16x8 r;
    r[0] = (short)f2bf(a[0]); r[1] = (short)f2bf(a[1]);
    r[2] = (short)f2bf(a[2]); r[3] = (short)f2bf(a[3]);
    r[4] = (short)f2bf(b[0]); r[5] = (short)f2bf(b[1]);
    r[6] = (short)f2bf(b[2]); r[7] = (short)f2bf(b[3]);
    return r;
}

// ---- prep: PA[b,i,c] = b2[c] + sum_k x1[b,i,k] W2[k][c]
//            PB[b,i,c] =         sum_k x1[b,i,k] W2[128+k][c]
__global__ void prep_pab(const float* __restrict__ x1, const float* __restrict__ W2,
                         const float* __restrict__ b2,
                         float* __restrict__ PA, float* __restrict__ PB) {
    int blk = blockIdx.x;          // b*128 + i
    int c = threadIdx.x;           // 0..63
    __shared__ float xv[64];
    xv[c] = x1[blk * 64 + c];
    __syncthreads();
    float accA = b2[c];
    float accB = 0.f;
#pragma unroll 8
    for (int k = 0; k < 64; ++k) {
        float xk = xv[k];
        accA += xk * W2[k * 64 + c];
        accB += xk * W2[(128 + k) * 64 + c];
    }
    PA[blk * 64 + c] = accA;
    PB[blk * 64 + c] = accB;
}

// ---- prep: WT[n][k] bf16, n<64, k<128. k<64 -> W2[64+k][n]; k>=64 -> W2[128+k][n]
__global__ void prep_wt(const float* __restrict__ W2, unsigned short* __restrict__ WT) {
    int idx = blockIdx.x * 256 + threadIdx.x;   // 0..8191
    int n = idx >> 7, k = idx & 127;
    int row = (k < 64) ? (64 + k) : (128 + k);
    WT[idx] = f2bf(W2[row * 64 + n]);
}

// ---- out0: [16,64]  (256 threads: float4 loads + shuffle reduce)
__global__ __launch_bounds__(256) void k_out0(const float* __restrict__ x0,
        const float* __restrict__ x1, const float* __restrict__ W0,
        const float* __restrict__ b0, float* __restrict__ out0) {
    int b = blockIdx.x;
    int t = threadIdx.x;
    int lane = t & 63, w = t >> 6;
    int q = lane & 15;             // c-quad
    int jq = lane >> 4;            // 0..3
    __shared__ float pw[4][64], pn[4][64], f0[136], spart[4][64];

    f32x4 mx = {-1e30f, -1e30f, -1e30f, -1e30f};
    f32x4 mn = {1e30f, 1e30f, 1e30f, 1e30f};
#pragma unroll
    for (int p = 0; p < 8; ++p) {
        int j = (w * 4 + jq) + 16 * p;
        float4 v = *reinterpret_cast<const float4*>(x1 + ((size_t)(b * 128 + j)) * 64 + q * 4);
        mx.x = fmaxf(mx.x, v.x); mx.y = fmaxf(mx.y, v.y);
        mx.z = fmaxf(mx.z, v.z); mx.w = fmaxf(mx.w, v.w);
        mn.x = fminf(mn.x, v.x); mn.y = fminf(mn.y, v.y);
        mn.z = fminf(mn.z, v.z); mn.w = fminf(mn.w, v.w);
    }
#pragma unroll
    for (int d = 16; d <= 32; d <<= 1) {
        mx.x = fmaxf(mx.x, __shfl_xor(mx.x, d)); mx.y = fmaxf(mx.y, __shfl_xor(mx.y, d));
        mx.z = fmaxf(mx.z, __shfl_xor(mx.z, d)); mx.w = fmaxf(mx.w, __shfl_xor(mx.w, d));
        mn.x = fminf(mn.x, __shfl_xor(mn.x, d)); mn.y = fminf(mn.y, __shfl_xor(mn.y, d));
        mn.z = fminf(mn.z, __shfl_xor(mn.z, d)); mn.w = fminf(mn.w, __shfl_xor(mn.w, d));
    }
    if (lane < 16) {
        *reinterpret_cast<f32x4*>(&pw[w][lane * 4]) = mx;
        *reinterpret_cast<f32x4*>(&pn[w][lane * 4]) = mn;
    }
    __syncthreads();
    if (t < 64) {
        int c = t;
        float M = fmaxf(fmaxf(pw[0][c], pw[1][c]), fmaxf(pw[2][c], pw[3][c]));
        float m = fminf(fminf(pn[0][c], pn[1][c]), fminf(pn[2][c], pn[3][c]));
        f0[8 + c] = M; f0[72 + c] = m;
        if (c < 8) f0[c] = x0[b * 8 + c];
    }
    __syncthreads();
    {
        int g = t >> 6, c = t & 63;
        float acc = 0.f;
#pragma unroll
        for (int k = g * 34; k < g * 34 + 34; ++k) acc += f0[k] * W0[k * 64 + c];
        spart[g][c] = acc;
    }
    __syncthreads();
    if (t < 64) {
        int c = t;
        out0[b * 64 + c] = sigmoidf_(spart[0][c] + spart[1][c] + spart[2][c] + spart[3][c] + b0[c]);
    }
}

// ---- main: supertile-pair kernel, zero LDS. 1152 blocks x 256 threads.
// wave-unit = blockIdx*4 + waveid; unit -> (supertile, s); supertile ->
// (b, gI<=gJ). Unit s handles output rows {R0+2s, R0+2s+1} for each side.
__global__ __launch_bounds__(256) void k_pair(const float* __restrict__ x2,
        const unsigned short* __restrict__ WT,
        const float* __restrict__ PA, const float* __restrict__ PB,
        float* __restrict__ pmax_ws, float* __restrict__ pmin_ws,
        float* __restrict__ out2) {
    int t = threadIdx.x;
    int lane = t & 63;
    int l15 = lane & 15, lh = lane >> 4;         // lh in 0..3
    int unit = blockIdx.x * 4 + (t >> 6);        // 0..4607
    int st = unit >> 3, s = unit & 7;            // supertile, sub-slot
    int b = st / 36;
    int r = st - b * 36;                         // triangular index 0..35
    int g = 0;
    while (r >= 8 - g) { r -= 8 - g; ++g; }      // 8 groups of 16
    int gI = g, gJ = g + r;
    int I0 = gI << 4, J0 = gJ << 4;
    int nsides = (gI == gJ) ? 1 : 2;
    bool diag = (gI == gJ);

    for (int side = 0; side < nsides; ++side) {
        int R0 = side ? J0 : I0;                 // group of output rows i
        int Cg = side ? I0 : J0;                 // group of output cols j
        int cgrp = side ? gI : gJ;
        int jcol = Cg + l15;                     // this lane's j
        for (int u = 0; u < 2; ++u) {
            int i = R0 + 2 * s + u;              // output row
            // ---- slab1 loads: x2[b,i,jcol,c], c = ks*32 + lh*8 + {0..7}
            const float* s1 = x2 + ((size_t)((b * 128 + i) * 128 + Cg)) * 64;
            f32x4 a00 = *reinterpret_cast<const f32x4*>(s1 + l15 * 64 + lh * 8);
            f32x4 a01 = *reinterpret_cast<const f32x4*>(s1 + l15 * 64 + lh * 8 + 4);
            f32x4 a10 = *reinterpret_cast<const f32x4*>(s1 + l15 * 64 + 32 + lh * 8);
            f32x4 a11 = *reinterpret_cast<const f32x4*>(s1 + l15 * 64 + 32 + lh * 8 + 4);
            // ---- slab2 loads: x2[b,jcol,i,c]
            const float* s2 = x2 + ((size_t)((b * 128 + jcol) * 128 + i)) * 64;
            f32x4 b00 = *reinterpret_cast<const f32x4*>(s2 + lh * 8);
            f32x4 b01 = *reinterpret_cast<const f32x4*>(s2 + lh * 8 + 4);
            f32x4 b10 = *reinterpret_cast<const f32x4*>(s2 + 32 + lh * 8);
            f32x4 b11 = *reinterpret_cast<const f32x4*>(s2 + 32 + lh * 8 + 4);

            // ---- out1 partials from slab1 (fp32-exact, exclude-self on diag)
            bool excl = diag && (l15 == (i - Cg));
            f32x4 mx00, mx01, mx10, mx11, mn00, mn01, mn10, mn11;
#pragma unroll
            for (int e = 0; e < 4; ++e) {
                mx00[e] = excl ? 0.f : a00[e]; mn00[e] = excl ? 1.f : a00[e];
                mx01[e] = excl ? 0.f : a01[e]; mn01[e] = excl ? 1.f : a01[e];
                mx10[e] = excl ? 0.f : a10[e]; mn10[e] = excl ? 1.f : a10[e];
                mx11[e] = excl ? 0.f : a11[e]; mn11[e] = excl ? 1.f : a11[e];
            }
#pragma unroll
            for (int d = 1; d <= 8; d <<= 1) {
#pragma unroll
                for (int e = 0; e < 4; ++e) {
                    mx00[e] = fmaxf(mx00[e], __shfl_xor(mx00[e], d));
                    mx01[e] = fmaxf(mx01[e], __shfl_xor(mx01[e], d));
                    mx10[e] = fmaxf(mx10[e], __shfl_xor(mx10[e], d));
                    mx11[e] = fmaxf(mx11[e], __shfl_xor(mx11[e], d));
                    mn00[e] = fminf(mn00[e], __shfl_xor(mn00[e], d));
                    mn01[e] = fminf(mn01[e], __shfl_xor(mn01[e], d));
                    mn10[e] = fminf(mn10[e], __shfl_xor(mn10[e], d));
                    mn11[e] = fminf(mn11[e], __shfl_xor(mn11[e], d));
                }
            }
            if (l15 == 0) {
                int slot = ((b * 128 + i) * 8 + cgrp) * 64;
                *reinterpret_cast<f32x4*>(&pmax_ws[slot + lh * 8]) = mx00;
                *reinterpret_cast<f32x4*>(&pmax_ws[slot + lh * 8 + 4]) = mx01;
                *reinterpret_cast<f32x4*>(&pmax_ws[slot + 32 + lh * 8]) = mx10;
                *reinterpret_cast<f32x4*>(&pmax_ws[slot + 32 + lh * 8 + 4]) = mx11;
                *reinterpret_cast<f32x4*>(&pmin_ws[slot + lh * 8]) = mn00;
                *reinterpret_cast<f32x4*>(&pmin_ws[slot + lh * 8 + 4]) = mn01;
                *reinterpret_cast<f32x4*>(&pmin_ws[slot + 32 + lh * 8]) = mn10;
                *reinterpret_cast<f32x4*>(&pmin_ws[slot + 32 + lh * 8 + 4]) = mn11;
            }

            // ---- B-fragments (data side): col=l15 (j), k-chunk lh*8
            s16x8 B[4];
            B[0] = pack_bf(a00, a01);   // k =   0..31 slice
            B[1] = pack_bf(a10, a11);   // k =  32..63
            B[2] = pack_bf(b00, b01);   // k =  64..95
            B[3] = pack_bf(b10, b11);   // k = 96..127

            // ---- MFMA: A = weights (row=c_out), acc[mt] = 16c x 16j
            f32x4 acc[4];
#pragma unroll
            for (int mt = 0; mt < 4; ++mt) acc[mt] = (f32x4){0.f, 0.f, 0.f, 0.f};
#pragma unroll
            for (int mt = 0; mt < 4; ++mt) {
#pragma unroll
                for (int ks = 0; ks < 4; ++ks) {
                    s16x8 wf = *reinterpret_cast<const s16x8*>(
                        WT + (mt * 16 + l15) * 128 + ks * 32 + lh * 8);
                    acc[mt] = __builtin_amdgcn_mfma_f32_16x16x32_bf16(
                        wf, B[ks], acc[mt], 0, 0, 0);
                }
            }

            // ---- epilogue: D row m = lh*4+r -> c = mt*16+lh*4+r; col = l15 -> j
            const float* PAi = PA + (b * 128 + i) * 64;
            const float* PBj = PB + (b * 128 + jcol) * 64;
            float* outRow = out2 + ((size_t)((b * 128 + i) * 128 + jcol)) * 64;
#pragma unroll
            for (int mt = 0; mt < 4; ++mt) {
                f32x4 pa4 = *reinterpret_cast<const f32x4*>(PAi + mt * 16 + lh * 4);
                f32x4 pb4 = *reinterpret_cast<const f32x4*>(PBj + mt * 16 + lh * 4);
                f32x4 o;
#pragma unroll
                for (int rr = 0; rr < 4; ++rr)
                    o[rr] = sigmoidf_(acc[mt][rr] + pa4[rr] + pb4[rr]);
                *reinterpret_cast<f32x4*>(outRow + mt * 16 + lh * 4) = o;
            }
        }
    }
}

// ---- out1 tail: combine 8 ws partials + 200x64 matvec
__global__ __launch_bounds__(256) void k_out1_tail(const float* __restrict__ x0,
        const float* __restrict__ x1, const float* __restrict__ W1,
        const float* __restrict__ b1, const float* __restrict__ pmax_ws,
        const float* __restrict__ pmin_ws, float* __restrict__ out1) {
    int blk = blockIdx.x;          // b*128 + i
    int t = threadIdx.x;
    int c = t & 63, g = t >> 6;
    __shared__ float sf[200], spart[4][64];
    if (t < 64) {
        float M = 0.f, m = 1.f;
#pragma unroll
        for (int s = 0; s < 8; ++s) {
            M = fmaxf(M, pmax_ws[(blk * 8 + s) * 64 + c]);
            m = fminf(m, pmin_ws[(blk * 8 + s) * 64 + c]);
        }
        sf[72 + c] = M; sf[136 + c] = m;
        sf[8 + c] = x1[blk * 64 + c];
        if (c < 8) sf[c] = x0[(blk >> 7) * 8 + c];
    }
    __syncthreads();
    {
        float a = 0.f;
#pragma unroll 10
        for (int k = g * 50; k < g * 50 + 50; ++k) a += sf[k] * W1[k * 64 + c];
        spart[g][c] = a;
    }
    __syncthreads();
    if (t < 64) {
        out1[blk * 64 + c] = sigmoidf_(
            spart[0][c] + spart[1][c] + spart[2][c] + spart[3][c] + b1[c]);
    }
}

extern "C" void kernel_launch(void* const* d_in, const int* in_sizes, int n_in,
                              void* d_out, int out_size, void* d_ws, size_t ws_size,
                              hipStream_t stream) {
    const float* x0 = (const float*)d_in[0];
    const float* x1 = (const float*)d_in[1];
    const float* x2 = (const float*)d_in[2];
    const float* W0 = (const float*)d_in[3];
    const float* b0 = (const float*)d_in[4];
    const float* W1 = (const float*)d_in[5];
    const float* b1 = (const float*)d_in[6];
    const float* W2 = (const float*)d_in[7];
    const float* b2 = (const float*)d_in[8];

    float* out0 = (float*)d_out;
    float* out1 = out0 + 16 * 64;
    float* out2 = out1 + 16 * 128 * 64;

    float* PA = (float*)d_ws;                            // 16*128*64 f32 (512KB)
    float* PB = PA + 16 * 128 * 64;                      // 512KB
    unsigned short* WT = (unsigned short*)(PB + 16 * 128 * 64);  // 16KB
    float* pmax_ws = (float*)(WT + 64 * 128);            // 16384*64 f32 (4MB)
    float* pmin_ws = pmax_ws + 16384 * 64;               // 4MB

    prep_pab<<<16 * 128, 64, 0, stream>>>(x1, W2, b2, PA, PB);
    prep_wt<<<32, 256, 0, stream>>>(W2, WT);
    k_out0<<<16, 256, 0, stream>>>(x0, x1, W0, b0, out0);
    k_pair<<<1152, 256, 0, stream>>>(x2, WT, PA, PB, pmax_ws, pmin_ws, out2);
    k_out1_tail<<<16 * 128, 256, 0, stream>>>(x0, x1, W1, b1, pmax_ws, pmin_ws, out1);
}

// Round 5
// 74.170 us; speedup vs baseline: 1.0884x; 1.0884x over previous
//
#include <hip/hip_runtime.h>
#include <hip/hip_bf16.h>
#include <cstdint>

// DLM breadth-2 forward. B=16, n=128, C=64.
// out = [out0 (16*64) | out1 (16*128*64) | out2 (16*128*128*64)], fp32.
//
// out2[b,i,j,c] = sigmoid( PA[b,i,c] + PB[b,j,c]
//                          + x2[b,i,j,:]·W2[64:128,c] + x2[b,j,i,:]·W2[192:256,c] )
// with PA = x1·W2[0:64] + b2, PB = x1·W2[128:192]  (precomputed).
//
// k_pair: ONE output row-tile (i, 16-col group) per wave. 16384 balanced
// wave-units in 4096 blocks; XCD-chunked swizzle co-locates each symmetric
// (gI,gJ) pair's blocks on one XCD so the transposed 256B reads are L2-hot.
// W is the MFMA A-operand, x2 the B-operand: zero LDS, zero barriers.
// out1 exclude-self max/min partials from the fp32 slab1 loads -> ws;
// tail kernel combines 8 group-partials + 200x64 matvec.

#define NDIM 128
#define CDIM 64

typedef float f32x4 __attribute__((ext_vector_type(4)));
typedef short s16x8 __attribute__((ext_vector_type(8)));

__device__ __forceinline__ unsigned short f2bf(float f) {
    union { float f; unsigned int u; } v; v.f = f;
    unsigned int u = v.u;
    return (unsigned short)((u + 0x7FFFu + ((u >> 16) & 1u)) >> 16);  // RNE
}
__device__ __forceinline__ float sigmoidf_(float x) {
    return 1.0f / (1.0f + __expf(-x));
}
__device__ __forceinline__ s16x8 pack_bf(f32x4 a, f32x4 b) {
    s16x8 r;
    r[0] = (short)f2bf(a[0]); r[1] = (short)f2bf(a[1]);
    r[2] = (short)f2bf(a[2]); r[3] = (short)f2bf(a[3]);
    r[4] = (short)f2bf(b[0]); r[5] = (short)f2bf(b[1]);
    r[6] = (short)f2bf(b[2]); r[7] = (short)f2bf(b[3]);
    return r;
}

// ---- merged prep: blocks [0,512) -> PA/PB; [512,544) -> WT; [544,560) -> out0
__global__ __launch_bounds__(256) void k_prep(const float* __restrict__ x0,
        const float* __restrict__ x1, const float* __restrict__ W0,
        const float* __restrict__ b0, const float* __restrict__ W2,
        const float* __restrict__ b2, float* __restrict__ PA,
        float* __restrict__ PB, unsigned short* __restrict__ WT,
        float* __restrict__ out0) {
    int bb = blockIdx.x;
    int t = threadIdx.x;
    if (bb < 512) {
        // PA[b,i,c], PB[b,i,c]: wave-local (each wave one (b,i) row)
        int u = t >> 6, c = t & 63;
        int blk = bb * 4 + u;          // 0..2047
        __shared__ float xv[4][64];
        xv[u][c] = x1[blk * 64 + c];   // wave-local RAW; no barrier needed
        float accA = b2[c];
        float accB = 0.f;
#pragma unroll 8
        for (int k = 0; k < 64; ++k) {
            float xk = xv[u][k];
            accA += xk * W2[k * 64 + c];
            accB += xk * W2[(128 + k) * 64 + c];
        }
        PA[blk * 64 + c] = accA;
        PB[blk * 64 + c] = accB;
    } else if (bb < 544) {
        // WT[n][k] bf16: k<64 -> W2[64+k][n]; k>=64 -> W2[128+k][n]
        int idx = (bb - 512) * 256 + t;   // 0..8191
        int n = idx >> 7, k = idx & 127;
        int row = (k < 64) ? (64 + k) : (128 + k);
        WT[idx] = f2bf(W2[row * 64 + n]);
    } else {
        // out0
        int b = bb - 544;
        int lane = t & 63, w = t >> 6;
        int q = lane & 15;
        int jq = lane >> 4;
        __shared__ float pw[4][64], pn[4][64], f0[136], spart[4][64];
        f32x4 mx = {-1e30f, -1e30f, -1e30f, -1e30f};
        f32x4 mn = {1e30f, 1e30f, 1e30f, 1e30f};
#pragma unroll
        for (int p = 0; p < 8; ++p) {
            int j = (w * 4 + jq) + 16 * p;
            float4 v = *reinterpret_cast<const float4*>(
                x1 + ((size_t)(b * 128 + j)) * 64 + q * 4);
            mx.x = fmaxf(mx.x, v.x); mx.y = fmaxf(mx.y, v.y);
            mx.z = fmaxf(mx.z, v.z); mx.w = fmaxf(mx.w, v.w);
            mn.x = fminf(mn.x, v.x); mn.y = fminf(mn.y, v.y);
            mn.z = fminf(mn.z, v.z); mn.w = fminf(mn.w, v.w);
        }
#pragma unroll
        for (int d = 16; d <= 32; d <<= 1) {
            mx.x = fmaxf(mx.x, __shfl_xor(mx.x, d)); mx.y = fmaxf(mx.y, __shfl_xor(mx.y, d));
            mx.z = fmaxf(mx.z, __shfl_xor(mx.z, d)); mx.w = fmaxf(mx.w, __shfl_xor(mx.w, d));
            mn.x = fminf(mn.x, __shfl_xor(mn.x, d)); mn.y = fminf(mn.y, __shfl_xor(mn.y, d));
            mn.z = fminf(mn.z, __shfl_xor(mn.z, d)); mn.w = fminf(mn.w, __shfl_xor(mn.w, d));
        }
        if (lane < 16) {
            *reinterpret_cast<f32x4*>(&pw[w][lane * 4]) = mx;
            *reinterpret_cast<f32x4*>(&pn[w][lane * 4]) = mn;
        }
        __syncthreads();
        if (t < 64) {
            int c = t;
            float M = fmaxf(fmaxf(pw[0][c], pw[1][c]), fmaxf(pw[2][c], pw[3][c]));
            float m = fminf(fminf(pn[0][c], pn[1][c]), fminf(pn[2][c], pn[3][c]));
            f0[8 + c] = M; f0[72 + c] = m;
            if (c < 8) f0[c] = x0[b * 8 + c];
        }
        __syncthreads();
        {
            int g = t >> 6, c = t & 63;
            float acc = 0.f;
#pragma unroll
            for (int k = g * 34; k < g * 34 + 34; ++k) acc += f0[k] * W0[k * 64 + c];
            spart[g][c] = acc;
        }
        __syncthreads();
        if (t < 64) {
            int c = t;
            out0[b * 64 + c] = sigmoidf_(
                spart[0][c] + spart[1][c] + spart[2][c] + spart[3][c] + b0[c]);
        }
    }
}

// ---- main: one row-tile per wave, zero LDS. 4096 blocks x 256 threads.
__global__ __launch_bounds__(256) void k_pair(const float* __restrict__ x2,
        const unsigned short* __restrict__ WT,
        const float* __restrict__ PA, const float* __restrict__ PB,
        float* __restrict__ pmax_ws, float* __restrict__ pmin_ws,
        float* __restrict__ out2) {
    int t = threadIdx.x;
    int lane = t & 63, w = t >> 6;
    int l15 = lane & 15, lh = lane >> 4;             // lh in 0..3

    // XCD-chunked bijective swizzle: 4096 = 8 XCD * 512
    int L = ((blockIdx.x & 7) << 9) | (blockIdx.x >> 3);
    int b = L >> 8;                                  // 0..15
    int e = L & 255;                                 // block-slot within batch

    int gI, gJ, side, row;
    if (e < 224) {                                   // off-diagonal pairs
        int pd = e >> 3, slot = e & 7;
        int rr = pd; gI = 0;
        while (rr >= 7 - gI) { rr -= 7 - gI; ++gI; }
        gJ = gI + 1 + rr;
        int r4 = slot * 4 + w;                       // 0..31
        side = r4 >> 4; row = r4 & 15;
    } else {                                         // diagonal groups
        int d = e - 224;
        gI = d >> 2; gJ = gI;
        int slot = d & 3;
        side = 0; row = slot * 4 + w;                // 0..15
    }
    bool diag = (gI == gJ);
    int I0 = gI << 4, J0 = gJ << 4;
    int i = (side ? J0 : I0) + row;                  // output row
    int Cg = side ? I0 : J0;                         // 16-col group base
    int cgrp = side ? gI : gJ;
    int jcol = Cg + l15;

    // ---- slab1: x2[b,i,jcol,c]  (contiguous 4KB per wave)
    const float* s1 = x2 + ((size_t)((b * 128 + i) * 128 + Cg)) * 64;
    f32x4 a00 = *reinterpret_cast<const f32x4*>(s1 + l15 * 64 + lh * 8);
    f32x4 a01 = *reinterpret_cast<const f32x4*>(s1 + l15 * 64 + lh * 8 + 4);
    f32x4 a10 = *reinterpret_cast<const f32x4*>(s1 + l15 * 64 + 32 + lh * 8);
    f32x4 a11 = *reinterpret_cast<const f32x4*>(s1 + l15 * 64 + 32 + lh * 8 + 4);
    // ---- slab2: x2[b,jcol,i,c]  (16 x 256B, L2-hot via pair co-location)
    const float* s2 = x2 + ((size_t)((b * 128 + jcol) * 128 + i)) * 64;
    f32x4 b00 = *reinterpret_cast<const f32x4*>(s2 + lh * 8);
    f32x4 b01 = *reinterpret_cast<const f32x4*>(s2 + lh * 8 + 4);
    f32x4 b10 = *reinterpret_cast<const f32x4*>(s2 + 32 + lh * 8);
    f32x4 b11 = *reinterpret_cast<const f32x4*>(s2 + 32 + lh * 8 + 4);

    // ---- out1 partials from slab1 (fp32-exact, exclude-self on diag)
    bool excl = diag && (l15 == row);
    f32x4 mx00, mx01, mx10, mx11, mn00, mn01, mn10, mn11;
#pragma unroll
    for (int e4 = 0; e4 < 4; ++e4) {
        mx00[e4] = excl ? 0.f : a00[e4]; mn00[e4] = excl ? 1.f : a00[e4];
        mx01[e4] = excl ? 0.f : a01[e4]; mn01[e4] = excl ? 1.f : a01[e4];
        mx10[e4] = excl ? 0.f : a10[e4]; mn10[e4] = excl ? 1.f : a10[e4];
        mx11[e4] = excl ? 0.f : a11[e4]; mn11[e4] = excl ? 1.f : a11[e4];
    }
#pragma unroll
    for (int d = 1; d <= 8; d <<= 1) {
#pragma unroll
        for (int e4 = 0; e4 < 4; ++e4) {
            mx00[e4] = fmaxf(mx00[e4], __shfl_xor(mx00[e4], d));
            mx01[e4] = fmaxf(mx01[e4], __shfl_xor(mx01[e4], d));
            mx10[e4] = fmaxf(mx10[e4], __shfl_xor(mx10[e4], d));
            mx11[e4] = fmaxf(mx11[e4], __shfl_xor(mx11[e4], d));
            mn00[e4] = fminf(mn00[e4], __shfl_xor(mn00[e4], d));
            mn01[e4] = fminf(mn01[e4], __shfl_xor(mn01[e4], d));
            mn10[e4] = fminf(mn10[e4], __shfl_xor(mn10[e4], d));
            mn11[e4] = fminf(mn11[e4], __shfl_xor(mn11[e4], d));
        }
    }
    if (l15 == 0) {
        int slot = ((b * 128 + i) * 8 + cgrp) * 64;
        *reinterpret_cast<f32x4*>(&pmax_ws[slot + lh * 8]) = mx00;
        *reinterpret_cast<f32x4*>(&pmax_ws[slot + lh * 8 + 4]) = mx01;
        *reinterpret_cast<f32x4*>(&pmax_ws[slot + 32 + lh * 8]) = mx10;
        *reinterpret_cast<f32x4*>(&pmax_ws[slot + 32 + lh * 8 + 4]) = mx11;
        *reinterpret_cast<f32x4*>(&pmin_ws[slot + lh * 8]) = mn00;
        *reinterpret_cast<f32x4*>(&pmin_ws[slot + lh * 8 + 4]) = mn01;
        *reinterpret_cast<f32x4*>(&pmin_ws[slot + 32 + lh * 8]) = mn10;
        *reinterpret_cast<f32x4*>(&pmin_ws[slot + 32 + lh * 8 + 4]) = mn11;
    }

    // ---- B-fragments (data side): col=l15 (j), k = ks*32 + lh*8 + e
    s16x8 B[4];
    B[0] = pack_bf(a00, a01);   // k =   0..31
    B[1] = pack_bf(a10, a11);   // k =  32..63
    B[2] = pack_bf(b00, b01);   // k =  64..95
    B[3] = pack_bf(b10, b11);   // k = 96..127

    // ---- MFMA: A = weights (row = out-channel), acc[mt] = 16c x 16j
    f32x4 acc[4];
#pragma unroll
    for (int mt = 0; mt < 4; ++mt) acc[mt] = (f32x4){0.f, 0.f, 0.f, 0.f};
#pragma unroll
    for (int mt = 0; mt < 4; ++mt) {
#pragma unroll
        for (int ks = 0; ks < 4; ++ks) {
            s16x8 wf = *reinterpret_cast<const s16x8*>(
                WT + (mt * 16 + l15) * 128 + ks * 32 + lh * 8);
            acc[mt] = __builtin_amdgcn_mfma_f32_16x16x32_bf16(wf, B[ks], acc[mt], 0, 0, 0);
        }
    }

    // ---- epilogue: D row m = lh*4+r -> c = mt*16+lh*4+r; col = l15 -> j
    const float* PAi = PA + (b * 128 + i) * 64;
    const float* PBj = PB + (b * 128 + jcol) * 64;
    float* outRow = out2 + ((size_t)((b * 128 + i) * 128 + jcol)) * 64;
#pragma unroll
    for (int mt = 0; mt < 4; ++mt) {
        f32x4 pa4 = *reinterpret_cast<const f32x4*>(PAi + mt * 16 + lh * 4);
        f32x4 pb4 = *reinterpret_cast<const f32x4*>(PBj + mt * 16 + lh * 4);
        f32x4 o;
#pragma unroll
        for (int rr2 = 0; rr2 < 4; ++rr2)
            o[rr2] = sigmoidf_(acc[mt][rr2] + pa4[rr2] + pb4[rr2]);
        *reinterpret_cast<f32x4*>(outRow + mt * 16 + lh * 4) = o;
    }
}

// ---- out1 tail: combine 8 ws partials + 200x64 matvec
__global__ __launch_bounds__(256) void k_out1_tail(const float* __restrict__ x0,
        const float* __restrict__ x1, const float* __restrict__ W1,
        const float* __restrict__ b1, const float* __restrict__ pmax_ws,
        const float* __restrict__ pmin_ws, float* __restrict__ out1) {
    int blk = blockIdx.x;          // b*128 + i
    int t = threadIdx.x;
    int c = t & 63, g = t >> 6;
    __shared__ float sf[200], spart[4][64];
    if (t < 64) {
        float M = 0.f, m = 1.f;
#pragma unroll
        for (int s = 0; s < 8; ++s) {
            M = fmaxf(M, pmax_ws[(blk * 8 + s) * 64 + c]);
            m = fminf(m, pmin_ws[(blk * 8 + s) * 64 + c]);
        }
        sf[72 + c] = M; sf[136 + c] = m;
        sf[8 + c] = x1[blk * 64 + c];
        if (c < 8) sf[c] = x0[(blk >> 7) * 8 + c];
    }
    __syncthreads();
    {
        float a = 0.f;
#pragma unroll 10
        for (int k = g * 50; k < g * 50 + 50; ++k) a += sf[k] * W1[k * 64 + c];
        spart[g][c] = a;
    }
    __syncthreads();
    if (t < 64) {
        out1[blk * 64 + c] = sigmoidf_(
            spart[0][c] + spart[1][c] + spart[2][c] + spart[3][c] + b1[c]);
    }
}

extern "C" void kernel_launch(void* const* d_in, const int* in_sizes, int n_in,
                              void* d_out, int out_size, void* d_ws, size_t ws_size,
                              hipStream_t stream) {
    const float* x0 = (const float*)d_in[0];
    const float* x1 = (const float*)d_in[1];
    const float* x2 = (const float*)d_in[2];
    const float* W0 = (const float*)d_in[3];
    const float* b0 = (const float*)d_in[4];
    const float* W1 = (const float*)d_in[5];
    const float* b1 = (const float*)d_in[6];
    const float* W2 = (const float*)d_in[7];
    const float* b2 = (const float*)d_in[8];

    float* out0 = (float*)d_out;
    float* out1 = out0 + 16 * 64;
    float* out2 = out1 + 16 * 128 * 64;

    float* PA = (float*)d_ws;                            // 16*128*64 f32 (512KB)
    float* PB = PA + 16 * 128 * 64;                      // 512KB
    unsigned short* WT = (unsigned short*)(PB + 16 * 128 * 64);  // 16KB
    float* pmax_ws = (float*)(WT + 64 * 128);            // 16384*64 f32 (4MB)
    float* pmin_ws = pmax_ws + 16384 * 64;               // 4MB

    k_prep<<<560, 256, 0, stream>>>(x0, x1, W0, b0, W2, b2, PA, PB, WT, out0);
    k_pair<<<4096, 256, 0, stream>>>(x2, WT, PA, PB, pmax_ws, pmin_ws, out2);
    k_out1_tail<<<16 * 128, 256, 0, stream>>>(x0, x1, W1, b1, pmax_ws, pmin_ws, out1);
}

// Round 6
// 68.394 us; speedup vs baseline: 1.1803x; 1.0845x over previous
//
#include <hip/hip_runtime.h>
#include <hip/hip_bf16.h>
#include <cstdint>

// DLM breadth-2 forward. B=16, n=128, C=64.
// out = [out0 (16*64) | out1 (16*128*64) | out2 (16*128*128*64)], fp32.
//
// out2[b,i,j,c] = sigmoid( PA[b,i,c] + PB[b,j,c]
//                          + x2[b,i,j,:]·W2[64:128,c] + x2[b,j,i,:]·W2[192:256,c] )
// with PA = x1·W2[0:64] + b2, PB = x1·W2[128:192]  (precomputed).
//
// k_fused (R1 structure + occupancy fixes): one block per (b,i); wave w owns
// j-rows [32w,32w+32). Barrier-free GEMM (each wave stages/consumes only its
// own LDS rows). LDS = exactly 32KB (Ald only; 5 blocks/CU): out1 partials
// ride in registers through MFMA, tail aliases Ald after __syncthreads().
// XCD-chunked swizzle co-locates consecutive (b,i) per XCD for L2 reuse.

#define NDIM 128
#define CDIM 64

typedef float f32x4 __attribute__((ext_vector_type(4)));
typedef short s16x8 __attribute__((ext_vector_type(8)));

__device__ __forceinline__ unsigned short f2bf(float f) {
    union { float f; unsigned int u; } v; v.f = f;
    unsigned int u = v.u;
    return (unsigned short)((u + 0x7FFFu + ((u >> 16) & 1u)) >> 16);  // RNE
}
__device__ __forceinline__ float sigmoidf_(float x) {
    return 1.0f / (1.0f + __expf(-x));
}

// ---- merged prep: blocks [0,512) -> PA/PB; [512,544) -> WT; [544,560) -> out0
__global__ __launch_bounds__(256) void k_prep(const float* __restrict__ x0,
        const float* __restrict__ x1, const float* __restrict__ W0,
        const float* __restrict__ b0, const float* __restrict__ W2,
        const float* __restrict__ b2, float* __restrict__ PA,
        float* __restrict__ PB, unsigned short* __restrict__ WT,
        float* __restrict__ out0) {
    int bb = blockIdx.x;
    int t = threadIdx.x;
    if (bb < 512) {
        int u = t >> 6, c = t & 63;
        int blk = bb * 4 + u;          // 0..2047
        __shared__ float xv[4][64];
        xv[u][c] = x1[blk * 64 + c];   // wave-local RAW
        float accA = b2[c];
        float accB = 0.f;
#pragma unroll 8
        for (int k = 0; k < 64; ++k) {
            float xk = xv[u][k];
            accA += xk * W2[k * 64 + c];
            accB += xk * W2[(128 + k) * 64 + c];
        }
        PA[blk * 64 + c] = accA;
        PB[blk * 64 + c] = accB;
    } else if (bb < 544) {
        int idx = (bb - 512) * 256 + t;   // 0..8191
        int n = idx >> 7, k = idx & 127;
        int row = (k < 64) ? (64 + k) : (128 + k);
        WT[idx] = f2bf(W2[row * 64 + n]);
    } else {
        int b = bb - 544;
        int lane = t & 63, w = t >> 6;
        int q = lane & 15;
        int jq = lane >> 4;
        __shared__ float pw[4][64], pn[4][64], f0[136], spart[4][64];
        f32x4 mx = {-1e30f, -1e30f, -1e30f, -1e30f};
        f32x4 mn = {1e30f, 1e30f, 1e30f, 1e30f};
#pragma unroll
        for (int p = 0; p < 8; ++p) {
            int j = (w * 4 + jq) + 16 * p;
            float4 v = *reinterpret_cast<const float4*>(
                x1 + ((size_t)(b * 128 + j)) * 64 + q * 4);
            mx.x = fmaxf(mx.x, v.x); mx.y = fmaxf(mx.y, v.y);
            mx.z = fmaxf(mx.z, v.z); mx.w = fmaxf(mx.w, v.w);
            mn.x = fminf(mn.x, v.x); mn.y = fminf(mn.y, v.y);
            mn.z = fminf(mn.z, v.z); mn.w = fminf(mn.w, v.w);
        }
#pragma unroll
        for (int d = 16; d <= 32; d <<= 1) {
            mx.x = fmaxf(mx.x, __shfl_xor(mx.x, d)); mx.y = fmaxf(mx.y, __shfl_xor(mx.y, d));
            mx.z = fmaxf(mx.z, __shfl_xor(mx.z, d)); mx.w = fmaxf(mx.w, __shfl_xor(mx.w, d));
            mn.x = fminf(mn.x, __shfl_xor(mn.x, d)); mn.y = fminf(mn.y, __shfl_xor(mn.y, d));
            mn.z = fminf(mn.z, __shfl_xor(mn.z, d)); mn.w = fminf(mn.w, __shfl_xor(mn.w, d));
        }
        if (lane < 16) {
            *reinterpret_cast<f32x4*>(&pw[w][lane * 4]) = mx;
            *reinterpret_cast<f32x4*>(&pn[w][lane * 4]) = mn;
        }
        __syncthreads();
        if (t < 64) {
            int c = t;
            float M = fmaxf(fmaxf(pw[0][c], pw[1][c]), fmaxf(pw[2][c], pw[3][c]));
            float m = fminf(fminf(pn[0][c], pn[1][c]), fminf(pn[2][c], pn[3][c]));
            f0[8 + c] = M; f0[72 + c] = m;
            if (c < 8) f0[c] = x0[b * 8 + c];
        }
        __syncthreads();
        {
            int g = t >> 6, c = t & 63;
            float acc = 0.f;
#pragma unroll
            for (int k = g * 34; k < g * 34 + 34; ++k) acc += f0[k] * W0[k * 64 + c];
            spart[g][c] = acc;
        }
        __syncthreads();
        if (t < 64) {
            int c = t;
            out0[b * 64 + c] = sigmoidf_(
                spart[0][c] + spart[1][c] + spart[2][c] + spart[3][c] + b0[c]);
        }
    }
}

// ---- fused out1+out2: one block per (b,i). LDS = exactly 32KB.
__global__ __launch_bounds__(256, 5) void k_fused(const float* __restrict__ x0,
        const float* __restrict__ x1, const float* __restrict__ x2,
        const unsigned short* __restrict__ WT,
        const float* __restrict__ W1, const float* __restrict__ b1,
        const float* __restrict__ PA, const float* __restrict__ PB,
        float* __restrict__ out1, float* __restrict__ out2) {
    // XCD-chunked bijective swizzle: 2048 = 8 XCD * 256
    int blk = ((blockIdx.x & 7) << 8) | (blockIdx.x >> 3);
    int b = blk >> 7, i = blk & 127;
    int t = threadIdx.x;
    int lane = t & 63, w = t >> 6;
    int jq = lane >> 4;            // 0..3
    int cc = (lane & 15) * 4;      // c-quad base

    __shared__ __align__(16) unsigned char shraw[32768];
    unsigned short* Ald = reinterpret_cast<unsigned short*>(shraw);  // [128][128] swizzled
    // tail aliases (valid only after the post-epilogue __syncthreads)
    float* sfT = reinterpret_cast<float*>(shraw);            // [200]
    float* spartT = sfT + 256;                                // [4][64]
    float* pwT = spartT + 256;                                // [4][64]
    float* pnT = pwT + 256;                                   // [4][64]

    const float* xaSrc = x2 + (size_t)blk * (NDIM * CDIM);

    // ---- phase 1: xa rows (x2[b,i,j,:]) -> regs, max/min partials, LDS k=0..63
    float4 va[8];
#pragma unroll
    for (int p = 0; p < 8; ++p) {
        int j = 32 * w + p * 4 + jq;
        va[p] = *reinterpret_cast<const float4*>(xaSrc + j * 64 + cc);
    }
    f32x4 mx = {0.f, 0.f, 0.f, 0.f}, mn = {1.f, 1.f, 1.f, 1.f};  // diag fill values
#pragma unroll
    for (int p = 0; p < 8; ++p) {
        int j = 32 * w + p * 4 + jq;
        bool ok = (j != i);
        mx.x = fmaxf(mx.x, ok ? va[p].x : 0.0f); mx.y = fmaxf(mx.y, ok ? va[p].y : 0.0f);
        mx.z = fmaxf(mx.z, ok ? va[p].z : 0.0f); mx.w = fmaxf(mx.w, ok ? va[p].w : 0.0f);
        mn.x = fminf(mn.x, ok ? va[p].x : 1.0f); mn.y = fminf(mn.y, ok ? va[p].y : 1.0f);
        mn.z = fminf(mn.z, ok ? va[p].z : 1.0f); mn.w = fminf(mn.w, ok ? va[p].w : 1.0f);
        ushort4 u;
        u.x = f2bf(va[p].x); u.y = f2bf(va[p].y); u.z = f2bf(va[p].z); u.w = f2bf(va[p].w);
        *reinterpret_cast<ushort4*>(&Ald[j * 128 + (cc ^ ((j & 7) << 3))]) = u;
    }
    // reduce partials across the 4 jq groups; result replicated to all lanes
#pragma unroll
    for (int d = 16; d <= 32; d <<= 1) {
        mx.x = fmaxf(mx.x, __shfl_xor(mx.x, d)); mx.y = fmaxf(mx.y, __shfl_xor(mx.y, d));
        mx.z = fmaxf(mx.z, __shfl_xor(mx.z, d)); mx.w = fmaxf(mx.w, __shfl_xor(mx.w, d));
        mn.x = fminf(mn.x, __shfl_xor(mn.x, d)); mn.y = fminf(mn.y, __shfl_xor(mn.y, d));
        mn.z = fminf(mn.z, __shfl_xor(mn.z, d)); mn.w = fminf(mn.w, __shfl_xor(mn.w, d));
    }
    // mx/mn stay LIVE in registers until the tail (lanes 0-15 hold channels cc..cc+3)

    // ---- phase 2: xb rows (x2[b,j,i,:]) -> LDS k=64..127
#pragma unroll
    for (int p = 0; p < 8; ++p) {
        int j = 32 * w + p * 4 + jq;
        float4 v = *reinterpret_cast<const float4*>(
            x2 + ((size_t)((b * 128 + j) * 128 + i)) * 64 + cc);
        ushort4 u;
        u.x = f2bf(v.x); u.y = f2bf(v.y); u.z = f2bf(v.z); u.w = f2bf(v.w);
        *reinterpret_cast<ushort4*>(&Ald[j * 128 + ((64 + cc) ^ ((j & 7) << 3))]) = u;
    }

    // ---- B fragments from WT (L1/L2-hot)
    s16x8 bfrag[4][4];
#pragma unroll
    for (int ks = 0; ks < 4; ++ks)
#pragma unroll
        for (int nt = 0; nt < 4; ++nt) {
            int n = nt * 16 + (lane & 15);
            int k0 = ks * 32 + jq * 8;
            bfrag[ks][nt] = *reinterpret_cast<const s16x8*>(WT + n * 128 + k0);
        }

    f32x4 acc[2][4];
#pragma unroll
    for (int m = 0; m < 2; ++m)
#pragma unroll
        for (int nt = 0; nt < 4; ++nt) acc[m][nt] = (f32x4){0.f, 0.f, 0.f, 0.f};

    // wave-local LDS producer/consumer: fence compiler + in-wave lgkm ordering.
    asm volatile("s_waitcnt lgkmcnt(0)" ::: "memory");
    __builtin_amdgcn_sched_barrier(0);

    // ---- MFMA over own rows [32w, 32w+32)
#pragma unroll
    for (int ks = 0; ks < 4; ++ks) {
#pragma unroll
        for (int m = 0; m < 2; ++m) {
            int row = 32 * w + m * 16 + (lane & 15);
            int u8 = (ks * 4 + jq) * 8;            // ushort offset of 16B chunk
            s16x8 afrag = *reinterpret_cast<const s16x8*>(
                &Ald[row * 128 + (u8 ^ ((row & 7) << 3))]);
#pragma unroll
            for (int nt = 0; nt < 4; ++nt)
                acc[m][nt] = __builtin_amdgcn_mfma_f32_16x16x32_bf16(
                    afrag, bfrag[ks][nt], acc[m][nt], 0, 0, 0);
        }
    }

    // ---- out2 epilogue: D row=(lane>>4)*4+r (j), col=lane&15 (c)
    const float* PAi = PA + blk * 64;
    const float* PBb = PB + b * 128 * 64;
    float* outBase = out2 + (size_t)blk * (NDIM * CDIM);
#pragma unroll
    for (int m = 0; m < 2; ++m) {
        int jt = 32 * w + m * 16 + jq * 4;
#pragma unroll
        for (int nt = 0; nt < 4; ++nt) {
            int cp = nt * 16 + (lane & 15);
            float pav = PAi[cp];
#pragma unroll
            for (int r = 0; r < 4; ++r) {
                int j = jt + r;
                outBase[j * 64 + cp] = sigmoidf_(acc[m][nt][r] + pav + PBb[j * 64 + cp]);
            }
        }
    }

    // ---- out1 tail (Ald reads all done -> safe to alias LDS)
    __syncthreads();
    if (lane < 16) {
        *reinterpret_cast<f32x4*>(&pwT[w * 64 + lane * 4]) = mx;
        *reinterpret_cast<f32x4*>(&pnT[w * 64 + lane * 4]) = mn;
    }
    __syncthreads();
    int c = t & 63;
    if (t < 64) {
        float M = fmaxf(fmaxf(pwT[c], pwT[64 + c]), fmaxf(pwT[128 + c], pwT[192 + c]));
        float m2 = fminf(fminf(pnT[c], pnT[64 + c]), fminf(pnT[128 + c], pnT[192 + c]));
        sfT[72 + c] = M; sfT[136 + c] = m2;
        sfT[8 + c] = x1[blk * 64 + c];
        if (c < 8) sfT[c] = x0[b * 8 + c];
    }
    __syncthreads();
    {
        int g = t >> 6;
        float acc1 = 0.f;
#pragma unroll 10
        for (int k = g * 50; k < g * 50 + 50; ++k) acc1 += sfT[k] * W1[k * 64 + c];
        spartT[g * 64 + c] = acc1;
    }
    __syncthreads();
    if (t < 64) {
        out1[blk * 64 + c] = sigmoidf_(
            spartT[c] + spartT[64 + c] + spartT[128 + c] + spartT[192 + c] + b1[c]);
    }
}

extern "C" void kernel_launch(void* const* d_in, const int* in_sizes, int n_in,
                              void* d_out, int out_size, void* d_ws, size_t ws_size,
                              hipStream_t stream) {
    const float* x0 = (const float*)d_in[0];
    const float* x1 = (const float*)d_in[1];
    const float* x2 = (const float*)d_in[2];
    const float* W0 = (const float*)d_in[3];
    const float* b0 = (const float*)d_in[4];
    const float* W1 = (const float*)d_in[5];
    const float* b1 = (const float*)d_in[6];
    const float* W2 = (const float*)d_in[7];
    const float* b2 = (const float*)d_in[8];

    float* out0 = (float*)d_out;
    float* out1 = out0 + 16 * 64;
    float* out2 = out1 + 16 * 128 * 64;

    float* PA = (float*)d_ws;                            // 16*128*64 f32 (512KB)
    float* PB = PA + 16 * 128 * 64;                      // 512KB
    unsigned short* WT = (unsigned short*)(PB + 16 * 128 * 64);  // 16KB

    k_prep<<<560, 256, 0, stream>>>(x0, x1, W0, b0, W2, b2, PA, PB, WT, out0);
    k_fused<<<2048, 256, 0, stream>>>(x0, x1, x2, WT, W1, b1, PA, PB, out1, out2);
}

// Round 7
// 62.027 us; speedup vs baseline: 1.3015x; 1.1027x over previous
//
#include <hip/hip_runtime.h>
#include <hip/hip_bf16.h>
#include <cstdint>

// DLM breadth-2 forward. B=16, n=128, C=64.
// out = [out0 (16*64) | out1 (16*128*64) | out2 (16*128*128*64)], fp32.
//
// out2[b,i,j,c] = sigmoid( PA[b,i,c] + PB[b,j,c]
//                          + x2[b,i,j,:]·W2[64:128,c] + x2[b,j,i,:]·W2[192:256,c] )
// with PA = x1·W2[0:64] + b2, PB = x1·W2[128:192]  (precomputed).
//
// k_fused (R1 structure + ILP): one block per (b,i); wave w owns j-rows
// [32w,32w+32). ALL 16 float4 loads (xa+xb) issued before any consumption ->
// one exposed HBM latency per wave instead of two. Barrier-free GEMM (each
// wave stages/consumes only its own LDS rows). LDS = exactly 32KB (tail
// aliases Ald after __syncthreads). Natural block order (no XCD swizzle).

#define NDIM 128
#define CDIM 64

typedef float f32x4 __attribute__((ext_vector_type(4)));
typedef short s16x8 __attribute__((ext_vector_type(8)));

__device__ __forceinline__ unsigned short f2bf(float f) {
    union { float f; unsigned int u; } v; v.f = f;
    unsigned int u = v.u;
    return (unsigned short)((u + 0x7FFFu + ((u >> 16) & 1u)) >> 16);  // RNE
}
__device__ __forceinline__ float sigmoidf_(float x) {
    return 1.0f / (1.0f + __expf(-x));
}

// ---- merged prep: blocks [0,512) -> PA/PB; [512,544) -> WT; [544,560) -> out0
__global__ __launch_bounds__(256) void k_prep(const float* __restrict__ x0,
        const float* __restrict__ x1, const float* __restrict__ W0,
        const float* __restrict__ b0, const float* __restrict__ W2,
        const float* __restrict__ b2, float* __restrict__ PA,
        float* __restrict__ PB, unsigned short* __restrict__ WT,
        float* __restrict__ out0) {
    int bb = blockIdx.x;
    int t = threadIdx.x;
    if (bb < 512) {
        int u = t >> 6, c = t & 63;
        int blk = bb * 4 + u;          // 0..2047
        __shared__ float xv[4][64];
        xv[u][c] = x1[blk * 64 + c];   // wave-local RAW
        float accA = b2[c];
        float accB = 0.f;
#pragma unroll 8
        for (int k = 0; k < 64; ++k) {
            float xk = xv[u][k];
            accA += xk * W2[k * 64 + c];
            accB += xk * W2[(128 + k) * 64 + c];
        }
        PA[blk * 64 + c] = accA;
        PB[blk * 64 + c] = accB;
    } else if (bb < 544) {
        int idx = (bb - 512) * 256 + t;   // 0..8191
        int n = idx >> 7, k = idx & 127;
        int row = (k < 64) ? (64 + k) : (128 + k);
        WT[idx] = f2bf(W2[row * 64 + n]);
    } else {
        int b = bb - 544;
        int lane = t & 63, w = t >> 6;
        int q = lane & 15;
        int jq = lane >> 4;
        __shared__ float pw[4][64], pn[4][64], f0[136], spart[4][64];
        f32x4 mx = {-1e30f, -1e30f, -1e30f, -1e30f};
        f32x4 mn = {1e30f, 1e30f, 1e30f, 1e30f};
#pragma unroll
        for (int p = 0; p < 8; ++p) {
            int j = (w * 4 + jq) + 16 * p;
            float4 v = *reinterpret_cast<const float4*>(
                x1 + ((size_t)(b * 128 + j)) * 64 + q * 4);
            mx.x = fmaxf(mx.x, v.x); mx.y = fmaxf(mx.y, v.y);
            mx.z = fmaxf(mx.z, v.z); mx.w = fmaxf(mx.w, v.w);
            mn.x = fminf(mn.x, v.x); mn.y = fminf(mn.y, v.y);
            mn.z = fminf(mn.z, v.z); mn.w = fminf(mn.w, v.w);
        }
#pragma unroll
        for (int d = 16; d <= 32; d <<= 1) {
            mx.x = fmaxf(mx.x, __shfl_xor(mx.x, d)); mx.y = fmaxf(mx.y, __shfl_xor(mx.y, d));
            mx.z = fmaxf(mx.z, __shfl_xor(mx.z, d)); mx.w = fmaxf(mx.w, __shfl_xor(mx.w, d));
            mn.x = fminf(mn.x, __shfl_xor(mn.x, d)); mn.y = fminf(mn.y, __shfl_xor(mn.y, d));
            mn.z = fminf(mn.z, __shfl_xor(mn.z, d)); mn.w = fminf(mn.w, __shfl_xor(mn.w, d));
        }
        if (lane < 16) {
            *reinterpret_cast<f32x4*>(&pw[w][lane * 4]) = mx;
            *reinterpret_cast<f32x4*>(&pn[w][lane * 4]) = mn;
        }
        __syncthreads();
        if (t < 64) {
            int c = t;
            float M = fmaxf(fmaxf(pw[0][c], pw[1][c]), fmaxf(pw[2][c], pw[3][c]));
            float m = fminf(fminf(pn[0][c], pn[1][c]), fminf(pn[2][c], pn[3][c]));
            f0[8 + c] = M; f0[72 + c] = m;
            if (c < 8) f0[c] = x0[b * 8 + c];
        }
        __syncthreads();
        {
            int g = t >> 6, c = t & 63;
            float acc = 0.f;
#pragma unroll
            for (int k = g * 34; k < g * 34 + 34; ++k) acc += f0[k] * W0[k * 64 + c];
            spart[g][c] = acc;
        }
        __syncthreads();
        if (t < 64) {
            int c = t;
            out0[b * 64 + c] = sigmoidf_(
                spart[0][c] + spart[1][c] + spart[2][c] + spart[3][c] + b0[c]);
        }
    }
}

// ---- fused out1+out2: one block per (b,i). LDS = exactly 32KB.
__global__ __launch_bounds__(256) void k_fused(const float* __restrict__ x0,
        const float* __restrict__ x1, const float* __restrict__ x2,
        const unsigned short* __restrict__ WT,
        const float* __restrict__ W1, const float* __restrict__ b1,
        const float* __restrict__ PA, const float* __restrict__ PB,
        float* __restrict__ out1, float* __restrict__ out2) {
    int blk = blockIdx.x;          // b*128 + i (natural order)
    int b = blk >> 7, i = blk & 127;
    int t = threadIdx.x;
    int lane = t & 63, w = t >> 6;
    int jq = lane >> 4;            // 0..3
    int cc = (lane & 15) * 4;      // c-quad base

    __shared__ __align__(16) unsigned char shraw[32768];
    unsigned short* Ald = reinterpret_cast<unsigned short*>(shraw);  // [128][128] swizzled
    // tail aliases (valid only after the post-epilogue __syncthreads)
    float* sfT = reinterpret_cast<float*>(shraw);             // [200]
    float* spartT = sfT + 256;                                // [4][64]
    float* pwT = spartT + 256;                                // [4][64]
    float* pnT = pwT + 256;                                   // [4][64]

    const float* xaSrc = x2 + (size_t)blk * (NDIM * CDIM);

    // ---- issue ALL loads up front: 8 xa + 8 xb float4 in flight together
    float4 va[8], vb[8];
#pragma unroll
    for (int p = 0; p < 8; ++p) {
        int j = 32 * w + p * 4 + jq;
        va[p] = *reinterpret_cast<const float4*>(xaSrc + j * 64 + cc);
    }
#pragma unroll
    for (int p = 0; p < 8; ++p) {
        int j = 32 * w + p * 4 + jq;
        vb[p] = *reinterpret_cast<const float4*>(
            x2 + ((size_t)((b * 128 + j) * 128 + i)) * 64 + cc);
    }

    // ---- consume xa: max/min partials + pack -> LDS k=0..63 (hides xb latency)
    f32x4 mx = {0.f, 0.f, 0.f, 0.f}, mn = {1.f, 1.f, 1.f, 1.f};  // diag fill values
#pragma unroll
    for (int p = 0; p < 8; ++p) {
        int j = 32 * w + p * 4 + jq;
        bool ok = (j != i);
        mx.x = fmaxf(mx.x, ok ? va[p].x : 0.0f); mx.y = fmaxf(mx.y, ok ? va[p].y : 0.0f);
        mx.z = fmaxf(mx.z, ok ? va[p].z : 0.0f); mx.w = fmaxf(mx.w, ok ? va[p].w : 0.0f);
        mn.x = fminf(mn.x, ok ? va[p].x : 1.0f); mn.y = fminf(mn.y, ok ? va[p].y : 1.0f);
        mn.z = fminf(mn.z, ok ? va[p].z : 1.0f); mn.w = fminf(mn.w, ok ? va[p].w : 1.0f);
        ushort4 u;
        u.x = f2bf(va[p].x); u.y = f2bf(va[p].y); u.z = f2bf(va[p].z); u.w = f2bf(va[p].w);
        *reinterpret_cast<ushort4*>(&Ald[j * 128 + (cc ^ ((j & 7) << 3))]) = u;
    }
    // reduce partials across the 4 jq groups; result replicated to all lanes
#pragma unroll
    for (int d = 16; d <= 32; d <<= 1) {
        mx.x = fmaxf(mx.x, __shfl_xor(mx.x, d)); mx.y = fmaxf(mx.y, __shfl_xor(mx.y, d));
        mx.z = fmaxf(mx.z, __shfl_xor(mx.z, d)); mx.w = fmaxf(mx.w, __shfl_xor(mx.w, d));
        mn.x = fminf(mn.x, __shfl_xor(mn.x, d)); mn.y = fminf(mn.y, __shfl_xor(mn.y, d));
        mn.z = fminf(mn.z, __shfl_xor(mn.z, d)); mn.w = fminf(mn.w, __shfl_xor(mn.w, d));
    }
    // mx/mn stay LIVE in registers until the tail

    // ---- consume xb: pack -> LDS k=64..127
#pragma unroll
    for (int p = 0; p < 8; ++p) {
        int j = 32 * w + p * 4 + jq;
        ushort4 u;
        u.x = f2bf(vb[p].x); u.y = f2bf(vb[p].y); u.z = f2bf(vb[p].z); u.w = f2bf(vb[p].w);
        *reinterpret_cast<ushort4*>(&Ald[j * 128 + ((64 + cc) ^ ((j & 7) << 3))]) = u;
    }

    // ---- B fragments from WT (L1/L2-hot)
    s16x8 bfrag[4][4];
#pragma unroll
    for (int ks = 0; ks < 4; ++ks)
#pragma unroll
        for (int nt = 0; nt < 4; ++nt) {
            int n = nt * 16 + (lane & 15);
            int k0 = ks * 32 + jq * 8;
            bfrag[ks][nt] = *reinterpret_cast<const s16x8*>(WT + n * 128 + k0);
        }

    f32x4 acc[2][4];
#pragma unroll
    for (int m = 0; m < 2; ++m)
#pragma unroll
        for (int nt = 0; nt < 4; ++nt) acc[m][nt] = (f32x4){0.f, 0.f, 0.f, 0.f};

    // wave-local LDS producer/consumer: fence compiler + in-wave lgkm ordering.
    asm volatile("s_waitcnt lgkmcnt(0)" ::: "memory");
    __builtin_amdgcn_sched_barrier(0);

    // ---- MFMA over own rows [32w, 32w+32)
#pragma unroll
    for (int ks = 0; ks < 4; ++ks) {
#pragma unroll
        for (int m = 0; m < 2; ++m) {
            int row = 32 * w + m * 16 + (lane & 15);
            int u8 = (ks * 4 + jq) * 8;            // ushort offset of 16B chunk
            s16x8 afrag = *reinterpret_cast<const s16x8*>(
                &Ald[row * 128 + (u8 ^ ((row & 7) << 3))]);
#pragma unroll
            for (int nt = 0; nt < 4; ++nt)
                acc[m][nt] = __builtin_amdgcn_mfma_f32_16x16x32_bf16(
                    afrag, bfrag[ks][nt], acc[m][nt], 0, 0, 0);
        }
    }

    // ---- out2 epilogue: D row=(lane>>4)*4+r (j), col=lane&15 (c)
    const float* PAi = PA + blk * 64;
    const float* PBb = PB + b * 128 * 64;
    float* outBase = out2 + (size_t)blk * (NDIM * CDIM);
#pragma unroll
    for (int m = 0; m < 2; ++m) {
        int jt = 32 * w + m * 16 + jq * 4;
#pragma unroll
        for (int nt = 0; nt < 4; ++nt) {
            int cp = nt * 16 + (lane & 15);
            float pav = PAi[cp];
#pragma unroll
            for (int r = 0; r < 4; ++r) {
                int j = jt + r;
                outBase[j * 64 + cp] = sigmoidf_(acc[m][nt][r] + pav + PBb[j * 64 + cp]);
            }
        }
    }

    // ---- out1 tail (Ald reads all done -> safe to alias LDS)
    __syncthreads();
    if (lane < 16) {
        *reinterpret_cast<f32x4*>(&pwT[w * 64 + lane * 4]) = mx;
        *reinterpret_cast<f32x4*>(&pnT[w * 64 + lane * 4]) = mn;
    }
    __syncthreads();
    int c = t & 63;
    if (t < 64) {
        float M = fmaxf(fmaxf(pwT[c], pwT[64 + c]), fmaxf(pwT[128 + c], pwT[192 + c]));
        float m2 = fminf(fminf(pnT[c], pnT[64 + c]), fminf(pnT[128 + c], pnT[192 + c]));
        sfT[72 + c] = M; sfT[136 + c] = m2;
        sfT[8 + c] = x1[blk * 64 + c];
        if (c < 8) sfT[c] = x0[b * 8 + c];
    }
    __syncthreads();
    {
        int g = t >> 6;
        float acc1 = 0.f;
#pragma unroll 10
        for (int k = g * 50; k < g * 50 + 50; ++k) acc1 += sfT[k] * W1[k * 64 + c];
        spartT[g * 64 + c] = acc1;
    }
    __syncthreads();
    if (t < 64) {
        out1[blk * 64 + c] = sigmoidf_(
            spartT[c] + spartT[64 + c] + spartT[128 + c] + spartT[192 + c] + b1[c]);
    }
}

extern "C" void kernel_launch(void* const* d_in, const int* in_sizes, int n_in,
                              void* d_out, int out_size, void* d_ws, size_t ws_size,
                              hipStream_t stream) {
    const float* x0 = (const float*)d_in[0];
    const float* x1 = (const float*)d_in[1];
    const float* x2 = (const float*)d_in[2];
    const float* W0 = (const float*)d_in[3];
    const float* b0 = (const float*)d_in[4];
    const float* W1 = (const float*)d_in[5];
    const float* b1 = (const float*)d_in[6];
    const float* W2 = (const float*)d_in[7];
    const float* b2 = (const float*)d_in[8];

    float* out0 = (float*)d_out;
    float* out1 = out0 + 16 * 64;
    float* out2 = out1 + 16 * 128 * 64;

    float* PA = (float*)d_ws;                            // 16*128*64 f32 (512KB)
    float* PB = PA + 16 * 128 * 64;                      // 512KB
    unsigned short* WT = (unsigned short*)(PB + 16 * 128 * 64);  // 16KB

    k_prep<<<560, 256, 0, stream>>>(x0, x1, W0, b0, W2, b2, PA, PB, WT, out0);
    k_fused<<<2048, 256, 0, stream>>>(x0, x1, x2, WT, W1, b1, PA, PB, out1, out2);
}

// Round 8
// 52.821 us; speedup vs baseline: 1.5283x; 1.1743x over previous
//
#include <hip/hip_runtime.h>
#include <hip/hip_bf16.h>
#include <cstdint>

// DLM breadth-2 forward. B=16, n=128, C=64.
// out = [out0 (16*64) | out1 (16*128*64) | out2 (16*128*128*64)], fp32.
//
// out2[b,i,j,c] = sigmoid( PA[b,i,c] + PB[b,j,c]
//                          + x2[b,i,j,:]·W2[64:128,c] + x2[b,j,i,:]·W2[192:256,c] )
// with PA = x1·W2[0:64] + b2, PB = x1·W2[128:192]  (precomputed).
//
// k_main: one block per (b,i,half): 128 threads (2 waves), 16KB LDS ->
// up to 10 blocks/CU. Wave w owns local j-rows [32w,32w+32) of its 64-row
// half: stages its own LDS rows, consumes only them (barrier-free), exits
// immediately after the out2 stores (no serial tail holding residency).
// out1 exclude-self max/min partials ride in registers briefly, hit ws
// before phase 2; k_out1_tail combines 4 slots + 200x64 matvec.

#define NDIM 128
#define CDIM 64

typedef float f32x4 __attribute__((ext_vector_type(4)));
typedef short s16x8 __attribute__((ext_vector_type(8)));

__device__ __forceinline__ unsigned short f2bf(float f) {
    union { float f; unsigned int u; } v; v.f = f;
    unsigned int u = v.u;
    return (unsigned short)((u + 0x7FFFu + ((u >> 16) & 1u)) >> 16);  // RNE
}
__device__ __forceinline__ float sigmoidf_(float x) {
    return 1.0f / (1.0f + __expf(-x));
}

// ---- merged prep: blocks [0,512) -> PA/PB; [512,544) -> WT; [544,560) -> out0
__global__ __launch_bounds__(256) void k_prep(const float* __restrict__ x0,
        const float* __restrict__ x1, const float* __restrict__ W0,
        const float* __restrict__ b0, const float* __restrict__ W2,
        const float* __restrict__ b2, float* __restrict__ PA,
        float* __restrict__ PB, unsigned short* __restrict__ WT,
        float* __restrict__ out0) {
    int bb = blockIdx.x;
    int t = threadIdx.x;
    if (bb < 512) {
        int u = t >> 6, c = t & 63;
        int blk = bb * 4 + u;          // 0..2047
        __shared__ float xv[4][64];
        xv[u][c] = x1[blk * 64 + c];   // wave-local RAW
        float accA = b2[c];
        float accB = 0.f;
#pragma unroll 8
        for (int k = 0; k < 64; ++k) {
            float xk = xv[u][k];
            accA += xk * W2[k * 64 + c];
            accB += xk * W2[(128 + k) * 64 + c];
        }
        PA[blk * 64 + c] = accA;
        PB[blk * 64 + c] = accB;
    } else if (bb < 544) {
        int idx = (bb - 512) * 256 + t;   // 0..8191
        int n = idx >> 7, k = idx & 127;
        int row = (k < 64) ? (64 + k) : (128 + k);
        WT[idx] = f2bf(W2[row * 64 + n]);
    } else {
        int b = bb - 544;
        int lane = t & 63, w = t >> 6;
        int q = lane & 15;
        int jq = lane >> 4;
        __shared__ float pw[4][64], pn[4][64], f0[136], spart[4][64];
        f32x4 mx = {-1e30f, -1e30f, -1e30f, -1e30f};
        f32x4 mn = {1e30f, 1e30f, 1e30f, 1e30f};
#pragma unroll
        for (int p = 0; p < 8; ++p) {
            int j = (w * 4 + jq) + 16 * p;
            float4 v = *reinterpret_cast<const float4*>(
                x1 + ((size_t)(b * 128 + j)) * 64 + q * 4);
            mx.x = fmaxf(mx.x, v.x); mx.y = fmaxf(mx.y, v.y);
            mx.z = fmaxf(mx.z, v.z); mx.w = fmaxf(mx.w, v.w);
            mn.x = fminf(mn.x, v.x); mn.y = fminf(mn.y, v.y);
            mn.z = fminf(mn.z, v.z); mn.w = fminf(mn.w, v.w);
        }
#pragma unroll
        for (int d = 16; d <= 32; d <<= 1) {
            mx.x = fmaxf(mx.x, __shfl_xor(mx.x, d)); mx.y = fmaxf(mx.y, __shfl_xor(mx.y, d));
            mx.z = fmaxf(mx.z, __shfl_xor(mx.z, d)); mx.w = fmaxf(mx.w, __shfl_xor(mx.w, d));
            mn.x = fminf(mn.x, __shfl_xor(mn.x, d)); mn.y = fminf(mn.y, __shfl_xor(mn.y, d));
            mn.z = fminf(mn.z, __shfl_xor(mn.z, d)); mn.w = fminf(mn.w, __shfl_xor(mn.w, d));
        }
        if (lane < 16) {
            *reinterpret_cast<f32x4*>(&pw[w][lane * 4]) = mx;
            *reinterpret_cast<f32x4*>(&pn[w][lane * 4]) = mn;
        }
        __syncthreads();
        if (t < 64) {
            int c = t;
            float M = fmaxf(fmaxf(pw[0][c], pw[1][c]), fmaxf(pw[2][c], pw[3][c]));
            float m = fminf(fminf(pn[0][c], pn[1][c]), fminf(pn[2][c], pn[3][c]));
            f0[8 + c] = M; f0[72 + c] = m;
            if (c < 8) f0[c] = x0[b * 8 + c];
        }
        __syncthreads();
        {
            int g = t >> 6, c = t & 63;
            float acc = 0.f;
#pragma unroll
            for (int k = g * 34; k < g * 34 + 34; ++k) acc += f0[k] * W0[k * 64 + c];
            spart[g][c] = acc;
        }
        __syncthreads();
        if (t < 64) {
            int c = t;
            out0[b * 64 + c] = sigmoidf_(
                spart[0][c] + spart[1][c] + spart[2][c] + spart[3][c] + b0[c]);
        }
    }
}

// ---- main: one block per (b,i,half). 2 waves, 16KB LDS, barrier-free,
// no tail. Wave w owns local rows [32w,32w+32) of the 64-row half-tile.
__global__ __launch_bounds__(128) void k_main(const float* __restrict__ x2,
        const unsigned short* __restrict__ WT,
        const float* __restrict__ PA, const float* __restrict__ PB,
        float* __restrict__ pmax_ws, float* __restrict__ pmin_ws,
        float* __restrict__ out2) {
    int bid = blockIdx.x;          // 0..4095
    int blk = bid >> 1, half = bid & 1;
    int b = blk >> 7, i = blk & 127;
    int j0 = half << 6;
    int t = threadIdx.x;
    int lane = t & 63, w = t >> 6; // w in 0..1
    int jq = lane >> 4;            // 0..3
    int cc = (lane & 15) * 4;      // c-quad base

    __shared__ __align__(16) unsigned short Ald[64 * 128];   // 16KB, XOR-swizzled

    const float* xaSrc = x2 + (size_t)blk * (NDIM * CDIM);

    // ---- phase 1: xa rows (x2[b,i,j,:]) -> regs, max/min partials, LDS k=0..63
    float4 va[8];
#pragma unroll
    for (int p = 0; p < 8; ++p) {
        int jl = 32 * w + p * 4 + jq;
        va[p] = *reinterpret_cast<const float4*>(xaSrc + (j0 + jl) * 64 + cc);
    }
    f32x4 mx = {0.f, 0.f, 0.f, 0.f}, mn = {1.f, 1.f, 1.f, 1.f};  // diag fill values
#pragma unroll
    for (int p = 0; p < 8; ++p) {
        int jl = 32 * w + p * 4 + jq;
        bool ok = (j0 + jl != i);
        mx.x = fmaxf(mx.x, ok ? va[p].x : 0.0f); mx.y = fmaxf(mx.y, ok ? va[p].y : 0.0f);
        mx.z = fmaxf(mx.z, ok ? va[p].z : 0.0f); mx.w = fmaxf(mx.w, ok ? va[p].w : 0.0f);
        mn.x = fminf(mn.x, ok ? va[p].x : 1.0f); mn.y = fminf(mn.y, ok ? va[p].y : 1.0f);
        mn.z = fminf(mn.z, ok ? va[p].z : 1.0f); mn.w = fminf(mn.w, ok ? va[p].w : 1.0f);
        ushort4 u;
        u.x = f2bf(va[p].x); u.y = f2bf(va[p].y); u.z = f2bf(va[p].z); u.w = f2bf(va[p].w);
        *reinterpret_cast<ushort4*>(&Ald[jl * 128 + (cc ^ ((jl & 7) << 3))]) = u;
    }
    // reduce partials across the 4 jq groups; store to ws NOW (frees mx/mn)
#pragma unroll
    for (int d = 16; d <= 32; d <<= 1) {
        mx.x = fmaxf(mx.x, __shfl_xor(mx.x, d)); mx.y = fmaxf(mx.y, __shfl_xor(mx.y, d));
        mx.z = fmaxf(mx.z, __shfl_xor(mx.z, d)); mx.w = fmaxf(mx.w, __shfl_xor(mx.w, d));
        mn.x = fminf(mn.x, __shfl_xor(mn.x, d)); mn.y = fminf(mn.y, __shfl_xor(mn.y, d));
        mn.z = fminf(mn.z, __shfl_xor(mn.z, d)); mn.w = fminf(mn.w, __shfl_xor(mn.w, d));
    }
    if (lane < 16) {
        int slot = blk * 4 + half * 2 + w;
        *reinterpret_cast<f32x4*>(&pmax_ws[slot * 64 + cc]) = mx;
        *reinterpret_cast<f32x4*>(&pmin_ws[slot * 64 + cc]) = mn;
    }

    // ---- phase 2: xb rows (x2[b,j,i,:]) -> LDS k=64..127
#pragma unroll
    for (int p = 0; p < 8; ++p) {
        int jl = 32 * w + p * 4 + jq;
        float4 v = *reinterpret_cast<const float4*>(
            x2 + ((size_t)((b * 128 + j0 + jl) * 128 + i)) * 64 + cc);
        ushort4 u;
        u.x = f2bf(v.x); u.y = f2bf(v.y); u.z = f2bf(v.z); u.w = f2bf(v.w);
        *reinterpret_cast<ushort4*>(&Ald[jl * 128 + ((64 + cc) ^ ((jl & 7) << 3))]) = u;
    }

    // ---- B fragments from WT (L1/L2-hot)
    s16x8 bfrag[4][4];
#pragma unroll
    for (int ks = 0; ks < 4; ++ks)
#pragma unroll
        for (int nt = 0; nt < 4; ++nt) {
            int n = nt * 16 + (lane & 15);
            int k0 = ks * 32 + jq * 8;
            bfrag[ks][nt] = *reinterpret_cast<const s16x8*>(WT + n * 128 + k0);
        }

    f32x4 acc[2][4];
#pragma unroll
    for (int m = 0; m < 2; ++m)
#pragma unroll
        for (int nt = 0; nt < 4; ++nt) acc[m][nt] = (f32x4){0.f, 0.f, 0.f, 0.f};

    // wave-local LDS producer/consumer: fence compiler + in-wave lgkm ordering.
    asm volatile("s_waitcnt lgkmcnt(0)" ::: "memory");
    __builtin_amdgcn_sched_barrier(0);

    // ---- MFMA over own local rows [32w, 32w+32)
#pragma unroll
    for (int ks = 0; ks < 4; ++ks) {
#pragma unroll
        for (int m = 0; m < 2; ++m) {
            int rowl = 32 * w + m * 16 + (lane & 15);
            int u8 = (ks * 4 + jq) * 8;            // ushort offset of 16B chunk
            s16x8 afrag = *reinterpret_cast<const s16x8*>(
                &Ald[rowl * 128 + (u8 ^ ((rowl & 7) << 3))]);
#pragma unroll
            for (int nt = 0; nt < 4; ++nt)
                acc[m][nt] = __builtin_amdgcn_mfma_f32_16x16x32_bf16(
                    afrag, bfrag[ks][nt], acc[m][nt], 0, 0, 0);
        }
    }

    // ---- out2 epilogue: D row=(lane>>4)*4+r (local j), col=lane&15 (c)
    const float* PAi = PA + blk * 64;
    const float* PBb = PB + b * 128 * 64;
    float* outBase = out2 + (size_t)blk * (NDIM * CDIM);
#pragma unroll
    for (int m = 0; m < 2; ++m) {
        int jt = j0 + 32 * w + m * 16 + jq * 4;
#pragma unroll
        for (int nt = 0; nt < 4; ++nt) {
            int cp = nt * 16 + (lane & 15);
            float pav = PAi[cp];
#pragma unroll
            for (int r = 0; r < 4; ++r) {
                int j = jt + r;
                outBase[j * 64 + cp] = sigmoidf_(acc[m][nt][r] + pav + PBb[j * 64 + cp]);
            }
        }
    }
}

// ---- out1 tail: combine 4 ws partials + 200x64 matvec
__global__ __launch_bounds__(256) void k_out1_tail(const float* __restrict__ x0,
        const float* __restrict__ x1, const float* __restrict__ W1,
        const float* __restrict__ b1, const float* __restrict__ pmax_ws,
        const float* __restrict__ pmin_ws, float* __restrict__ out1) {
    int blk = blockIdx.x;          // b*128 + i
    int t = threadIdx.x;
    int c = t & 63, g = t >> 6;
    __shared__ float sf[200], spart[4][64];
    if (t < 64) {
        float M = 0.f, m = 1.f;
#pragma unroll
        for (int s = 0; s < 4; ++s) {
            M = fmaxf(M, pmax_ws[(blk * 4 + s) * 64 + c]);
            m = fminf(m, pmin_ws[(blk * 4 + s) * 64 + c]);
        }
        sf[72 + c] = M; sf[136 + c] = m;
        sf[8 + c] = x1[blk * 64 + c];
        if (c < 8) sf[c] = x0[(blk >> 7) * 8 + c];
    }
    __syncthreads();
    {
        float a = 0.f;
#pragma unroll 10
        for (int k = g * 50; k < g * 50 + 50; ++k) a += sf[k] * W1[k * 64 + c];
        spart[g][c] = a;
    }
    __syncthreads();
    if (t < 64) {
        out1[blk * 64 + c] = sigmoidf_(
            spart[0][c] + spart[1][c] + spart[2][c] + spart[3][c] + b1[c]);
    }
}

extern "C" void kernel_launch(void* const* d_in, const int* in_sizes, int n_in,
                              void* d_out, int out_size, void* d_ws, size_t ws_size,
                              hipStream_t stream) {
    const float* x0 = (const float*)d_in[0];
    const float* x1 = (const float*)d_in[1];
    const float* x2 = (const float*)d_in[2];
    const float* W0 = (const float*)d_in[3];
    const float* b0 = (const float*)d_in[4];
    const float* W1 = (const float*)d_in[5];
    const float* b1 = (const float*)d_in[6];
    const float* W2 = (const float*)d_in[7];
    const float* b2 = (const float*)d_in[8];

    float* out0 = (float*)d_out;
    float* out1 = out0 + 16 * 64;
    float* out2 = out1 + 16 * 128 * 64;

    float* PA = (float*)d_ws;                            // 16*128*64 f32 (512KB)
    float* PB = PA + 16 * 128 * 64;                      // 512KB
    unsigned short* WT = (unsigned short*)(PB + 16 * 128 * 64);  // 16KB
    float* pmax_ws = (float*)(WT + 64 * 128);            // 2048*4*64 f32 (2MB)
    float* pmin_ws = pmax_ws + 2048 * 4 * 64;            // 2MB

    k_prep<<<560, 256, 0, stream>>>(x0, x1, W0, b0, W2, b2, PA, PB, WT, out0);
    k_main<<<4096, 128, 0, stream>>>(x2, WT, PA, PB, pmax_ws, pmin_ws, out2);
    k_out1_tail<<<2048, 256, 0, stream>>>(x0, x1, W1, b1, pmax_ws, pmin_ws, out1);
}